// Round 8
// baseline (212.322 us; speedup 1.0000x reference)
//
#include <hip/hip_runtime.h>

typedef _Float16 v8h __attribute__((ext_vector_type(8)));
typedef float v16f __attribute__((ext_vector_type(16)));

// ---------------------------------------------------------------------------
// BF: B in MFMA-fragment order, padded to 66 ko (pad rows = 0).
// Fragment f = kk16*2 + nf holds at [lane*8 + j]:
//   B[k = kk16*16 + (lane>>5)*8 + j][o = nf*32 + (lane&31)]
// where B[k][o] = (ko<64) ? w2[ko, i*64+o] : (ko==64 ? b2[i*64+o] : 0),
// ko = k/IN, i = k%IN. kk16 = ko*PH + p.  (row 65 pad is never read.)
//
// prep_fused also computes agg0 = bias0 + x@root0 and emits x in f16.
// ---------------------------------------------------------------------------
__global__ void prep_fused(const float* __restrict__ w2_0, const float* __restrict__ b2_0,
                           _Float16* __restrict__ BF0,
                           const float* __restrict__ w2_1, const float* __restrict__ b2_1,
                           _Float16* __restrict__ BF1,
                           const float* __restrict__ x, const float* __restrict__ root,
                           const float* __restrict__ bias, float* __restrict__ agg,
                           _Float16* __restrict__ xb, int N) {
    int idx = blockIdx.x * 256 + threadIdx.x;
    const int n0 = 264 * 512;   // layer0: 66 ko * 2 kk16/ko * 2 nf
    const int n1 = 528 * 512;   // layer1: 66 ko * 4 kk16/ko * 2 nf
    if (idx < n0 + n1) {
        const float* w2; const float* b2; _Float16* BF; int IN, rel;
        if (idx < n0) { w2 = w2_0; b2 = b2_0; BF = BF0; IN = 32; rel = idx; }
        else          { w2 = w2_1; b2 = b2_1; BF = BF1; IN = 64; rel = idx - n0; }
        int j = rel & 7, lane = (rel >> 3) & 63, f = rel >> 9;
        int nf = f & 1, kk16 = f >> 1;
        int ln = lane & 31, g2 = lane >> 5;
        int k = kk16 * 16 + g2 * 8 + j;
        int ko = k / IN, i = k - ko * IN;
        int o = nf * 32 + ln;
        float v = (ko < 64) ? w2[ko * (IN * 64) + i * 64 + o]
                : (ko == 64 ? b2[i * 64 + o] : 0.f);
        BF[rel] = (_Float16)v;
        return;
    }
    idx -= (n0 + n1);
    if (idx >= N * 64) return;
    int n = idx >> 6, o = idx & 63;
    float s = bias[o];
    const float* xr = x + (size_t)n * 32;
    #pragma unroll 8
    for (int i = 0; i < 32; ++i) s += xr[i] * root[i * 64 + o];
    agg[idx] = s;
    if (o < 32) xb[n * 32 + o] = (_Float16)xr[o];
}

// x1b = f16(relu(agg0)); agg1[n,o] = bias1[o] + sum_i relu(agg0[n,i])*root1[i,o]
__global__ void mid_kernel(const float* __restrict__ agg0, const float* __restrict__ root1,
                           const float* __restrict__ bias1, _Float16* __restrict__ x1b,
                           float* __restrict__ agg1, int N) {
    int idx = blockIdx.x * 256 + threadIdx.x;
    if (idx >= N * 64) return;
    int n = idx >> 6, o = idx & 63;
    const float* ar = agg0 + (size_t)n * 64;
    float s = bias1[o];
    #pragma unroll 8
    for (int i = 0; i < 64; ++i) s += fmaxf(ar[i], 0.f) * root1[i * 64 + o];
    agg1[idx] = s;
    x1b[idx] = (_Float16)fmaxf(agg0[idx], 0.f);
}

__global__ void final_relu(const float* __restrict__ agg1, float* __restrict__ out, int n) {
    int idx = blockIdx.x * 256 + threadIdx.x;
    if (idx < n) out[idx] = fmaxf(agg1[idx], 0.f);
}

// ---------------------------------------------------------------------------
// Edge GEMM v13: ZERO-LDS, ZERO-BARRIER register-dataflow kernel.
// Evidence trail (v7-v12): dur ~41-48us and MfmaUtil ~20-24% invariant to
// waves/SIMD, tile size, bank conflicts, ko ordering, epilogue structure.
// The one thing every variant shared: scales (sh_r1) and x fragments lived
// in LDS, and at VGPR_Count 60-88 the compiler rematerialized them per ko,
// putting a ~120cyc ds_read -> VALU scale -> MFMA chain on EVERY ko plus
// ~100cyc/ko of LDS pipe occupancy. v13 removes LDS from the loop entirely:
//  - wave q owns ONE 32-edge slice and BOTH nf halves: the scaled A-fragment
//    feeds 2 MFMAs (VALU:matrix halves to 1:2).
//  - r1 scales computed PER-LANE into 9 v8h registers (lane's own edge;
//    w1/b1 uniform -> scalar loads). No sh_r1.
//  - x fragments gathered per-lane from global into registers (global loads
//    can't be rematerialized -> forced residency). No sh_x.
//  - K-loop (65 ko) fully unrolled: 8 B-loads + 16 pk_mul + 8 MFMA per ko,
//    all-register; compiler pipelines loads under the 256-VGPR budget.
//  - epilogue reads dstI directly; one atomic per output element.
// 512 threads = 8 waves = 2 waves/SIMD; LDS = 0 bytes; no __syncthreads.
// ---------------------------------------------------------------------------
template<int IN_C>
__global__ __launch_bounds__(512, 1)
void edge_gemm(const float* __restrict__ ea,
               const float* __restrict__ w1, const float* __restrict__ b1,
               const _Float16* __restrict__ xb, const _Float16* __restrict__ BF,
               const int* __restrict__ srcI, const int* __restrict__ dstI,
               float* __restrict__ agg, int E) {
    constexpr int PH = IN_C / 16;         // fragments per ko per nf
    constexpr int M  = 256;               // edges per block

    int tid  = threadIdx.x;
    int wv   = tid >> 6, lane = tid & 63, ln = lane & 31, g2 = lane >> 5;
    int q    = wv;                        // wave's 32-edge slice (0..7)
    int ebase = blockIdx.x * M;
    int valid = E - ebase; if (valid > M) valid = M;

    int e  = q * 32 + ln;                 // lane's own edge (row in A)
    int ge = (e < valid) ? (ebase + e) : ebase;

    // ---- per-lane r1 scales: sv[c][j] = relu(ea@w1+b1)[c*8+j]; sv[8]=bias row
    float a0 = ea[(size_t)ge * 2], a1 = ea[(size_t)ge * 2 + 1];
    v8h sv[9];
    #pragma unroll
    for (int c = 0; c < 8; ++c) {
        #pragma unroll
        for (int j = 0; j < 8; ++j) {
            int o = c * 8 + j;
            float h = fmaf(a0, w1[o], fmaf(a1, w1[64 + o], b1[o]));
            sv[c][j] = (_Float16)fmaxf(h, 0.f);
        }
    }
    #pragma unroll
    for (int j = 0; j < 8; ++j) sv[8][j] = (_Float16)0.f;
    sv[8][0] = (_Float16)1.f;             // scale 1 for the b2 row of BF

    // ---- per-lane x fragments from global (16B gather per fragment)
    int sidx = (e < valid) ? srcI[ebase + e] : 0;
    const _Float16* xr = xb + (size_t)sidx * IN_C;
    v8h xs[PH];
    #pragma unroll
    for (int p = 0; p < PH; ++p)
        xs[p] = *(const v8h*)(xr + p * 16 + g2 * 8);

    v16f acc0 = {0,0,0,0,0,0,0,0,0,0,0,0,0,0,0,0};   // nf = 0 (cols 0..31)
    v16f acc1 = acc0;                                 // nf = 1 (cols 32..63)

    // fragment stream: frag(ko,p,nf) at uint4 index (ko*PH+p)*128 + nf*64 + lane
    const uint4* bp = (const uint4*)BF + lane;

    #pragma unroll
    for (int ko = 0; ko < 65; ++ko) {
        _Float16 s = sv[ko >> 3][ko & 7];             // static after unroll
        #pragma unroll
        for (int p = 0; p < PH; ++p) {
            v8h a = xs[p] * s;
            uint4 u0 = bp[(size_t)(ko * PH + p) * 128];
            uint4 u1 = bp[(size_t)(ko * PH + p) * 128 + 64];
            v8h b0, b1v;
            __builtin_memcpy(&b0, &u0, 16);
            __builtin_memcpy(&b1v, &u1, 16);
            acc0 = __builtin_amdgcn_mfma_f32_32x32x16_f16(a, b0, acc0, 0, 0, 0);
            acc1 = __builtin_amdgcn_mfma_f32_32x32x16_f16(a, b1v, acc1, 0, 0, 0);
        }
    }

    // ---- epilogue: one atomic per output element; dst read straight from global
    #pragma unroll
    for (int r = 0; r < 16; ++r) {
        int rr = 4 * g2 + (r & 3) + 8 * (r >> 2);     // row within the 32-edge slice
        int er = q * 32 + rr;
        if (er < valid) {
            int d = dstI[ebase + er];
            atomicAdd(&agg[(size_t)d * 64 + ln],      acc0[r]);
            atomicAdd(&agg[(size_t)d * 64 + 32 + ln], acc1[r]);
        }
    }
}

// ---------------------------------------------------------------------------
extern "C" void kernel_launch(void* const* d_in, const int* in_sizes, int n_in,
                              void* d_out, int out_size, void* d_ws, size_t ws_size,
                              hipStream_t stream) {
    const float* x      = (const float*)d_in[0];
    const int*   ei     = (const int*)d_in[1];
    const float* ea     = (const float*)d_in[2];
    const float* w1_0   = (const float*)d_in[3];
    const float* b1_0   = (const float*)d_in[4];
    const float* w2_0   = (const float*)d_in[5];
    const float* b2_0   = (const float*)d_in[6];
    const float* root_0 = (const float*)d_in[7];
    const float* bias_0 = (const float*)d_in[8];
    const float* w1_1   = (const float*)d_in[9];
    const float* b1_1   = (const float*)d_in[10];
    const float* w2_1   = (const float*)d_in[11];
    const float* b2_1   = (const float*)d_in[12];
    const float* root_1 = (const float*)d_in[13];
    const float* bias_1 = (const float*)d_in[14];
    float* out = (float*)d_out;

    int N = in_sizes[0] / 32;
    int E = in_sizes[1] / 2;
    const int* srcI = ei;
    const int* dstI = ei + E;

    char* ws = (char*)d_ws;
    size_t off = 0;
    auto carve = [&](size_t bytes) {
        void* p = ws + off;
        off += (bytes + 255) & ~(size_t)255;
        return p;
    };
    _Float16* BF0  = (_Float16*)carve((size_t)264 * 512 * 2);
    _Float16* BF1  = (_Float16*)carve((size_t)528 * 512 * 2);
    _Float16* XB0  = (_Float16*)carve((size_t)N * 32 * 2);
    _Float16* X1B  = (_Float16*)carve((size_t)N * 64 * 2);
    float*    AGG0 = (float*)carve((size_t)N * 64 * 4);
    float*    AGG1 = (float*)carve((size_t)N * 64 * 4);

    int tprep = (264 + 528) * 512 + N * 64;
    prep_fused<<<(tprep + 255) / 256, 256, 0, stream>>>(w2_0, b2_0, BF0, w2_1, b2_1, BF1,
                                                        x, root_0, bias_0, AGG0, XB0, N);

    int gblocks = (E + 255) / 256;
    edge_gemm<32><<<gblocks, 512, 0, stream>>>(ea, w1_0, b1_0, XB0, BF0, srcI, dstI, AGG0, E);

    mid_kernel<<<(N * 64 + 255) / 256, 256, 0, stream>>>(AGG0, root_1, bias_1, X1B, AGG1, N);

    edge_gemm<64><<<gblocks, 512, 0, stream>>>(ea, w1_1, b1_1, X1B, BF1, srcI, dstI, AGG1, E);

    final_relu<<<(N * 64 + 255) / 256, 256, 0, stream>>>(AGG1, out, N * 64);
}